// Round 3
// baseline (159.297 us; speedup 1.0000x reference)
//
#include <hip/hip_runtime.h>

// RepulsionXTB: per-pair repulsion energy, segment-summed per molecule.
//
// Inputs (setup_inputs order, harness converts ints to int32):
//   d_in[0] element_idxs  int32  [M*A]   (M=2048, A=64 -> 131072)
//   d_in[1] neighbor_idxs int32  [2*P]   (P=8388608)
//   d_in[2] distances     f32    [P]
//   d_in[3] y_ab          f32    [16]
//   d_in[4] sqrt_alpha_ab f32    [16]
//   d_in[5] k_rep_ab      f32    [16]   (1.5 everywhere except [0,0]=1.0)
// Output: energies f32 [M]
//
// R6 notes: R4/R5 (intra-iteration batching) both failed -> LDS chains are
// not the lever. Remaining stall: each lane runs only 4 grid-stride
// iterations; compiler drains vmcnt(0) right after issuing the 3 loads, so
// every iteration eats a full L3/HBM latency (~700-900cy) -> lockstep
// convoys, VALU 16%, HBM 13%. This round: 1-deep register prefetch across
// the loop backedge (issue i+stride's loads, fence, process i) so the wait
// becomes vmcnt(3) with next loads in flight under the compute. Processing
// is R3's lean per-pair chain (branchless cutoff, magic-mul mol).

#define AB_D 1.8897261258369282
#define L2E  1.4426950408889634f   // log2(e)

// ---------------- kernel 1: pack species to 2 bits/atom + zero output -------
__global__ __launch_bounds__(256) void pack_zero_kernel(
    const int* __restrict__ elem, int natoms, int nwords,
    unsigned* __restrict__ packed, float* __restrict__ out, int M)
{
    int g = blockIdx.x * blockDim.x + threadIdx.x;
    if (g < M) out[g] = 0.0f;
    if (packed != nullptr && g < nwords) {
        int base = g * 16;
        unsigned w = 0u;
        if (base + 16 <= natoms) {
            const int4* p = (const int4*)(elem + base);
            #pragma unroll
            for (int q = 0; q < 4; ++q) {
                int4 v = p[q];
                w |= ((unsigned)v.x & 3u) << (2 * (4 * q + 0));
                w |= ((unsigned)v.y & 3u) << (2 * (4 * q + 1));
                w |= ((unsigned)v.z & 3u) << (2 * (4 * q + 2));
                w |= ((unsigned)v.w & 3u) << (2 * (4 * q + 3));
            }
        } else {
            for (int j = 0; j < 16; ++j) {
                int a = base + j;
                unsigned s = (a < natoms) ? ((unsigned)elem[a] & 3u) : 0u;
                w |= s << (2 * j);
            }
        }
        packed[g] = w;
    }
}

// ---------------- kernel 2: main pair loop ----------------------------------
// LDS layout: [acc: M f32][tbl: 16 float2][pk: nwords u32]
__global__ __launch_bounds__(1024, 8) void rep_main_kernel(
    const int* __restrict__ nbr, const float* __restrict__ dist,
    const unsigned* __restrict__ packed_g,
    const float* __restrict__ y_ab, const float* __restrict__ sa_ab,
    const float* __restrict__ kr_ab,
    long long P, int M, int nwords, unsigned long long molMagic, int A,
    float* __restrict__ partials, float* __restrict__ out,
    int mode /*0 = write partial row, 1 = global atomics*/)
{
    extern __shared__ char smem[];
    float*  acc = (float*)smem;
    float2* tbl = (float2*)(smem + (size_t)M * 4);
    unsigned* pk = (unsigned*)(smem + (size_t)M * 4 + 16 * sizeof(float2));

    const int tid = threadIdx.x;
    const int nthr = blockDim.x;

    for (int m = tid; m < M; m += nthr) acc[m] = 0.0f;
    for (int w = tid; w < nwords; w += nthr) pk[w] = packed_g[w];
    if (tid < 16) {
        float sa = sa_ab[tid] * L2E;           // pre-scale for exp2
        if (kr_ab[tid] == 1.0f) sa = -sa;      // sign bit encodes kr==1 (H-H)
        tbl[tid] = make_float2(y_ab[tid], sa);
    }
    __syncthreads();

    const float ABf   = (float)AB_D;
    const float DMIN  = (float)(1e-7 * AB_D);
    const float RCINV = (float)(1.0 / (5.2 * AB_D));

    const int4*   nb04 = (const int4*)nbr;
    const int4*   nb14 = (const int4*)(nbr + P);
    const float4* dv4  = (const float4*)dist;

    // per-pair chain: 2 pk reads -> tbl read -> VALU -> LDS atomic
    auto pair = [&](unsigned ua0, unsigned ua1, float draw) {
        unsigned w0 = pk[ua0 >> 4];
        unsigned w1 = pk[ua1 >> 4];
        unsigned s0 = (w0 >> ((ua0 & 15u) * 2u)) & 3u;
        unsigned s1 = (w1 >> ((ua1 & 15u) * 2u)) & 3u;
        float2 t = tbl[s0 * 4u + s1];
        float d   = fmaxf(draw * ABf, DMIN);
        float x   = d * RCINV;
        float om  = fmaxf(fmaf(-x, x, 1.0f), 0.0f); // 0 outside cutoff
        float r   = __builtin_amdgcn_rcpf(om);      // +inf outside
        float e   = fmaf(-L2E, r, L2E);             // -inf outside
        float sq  = __builtin_amdgcn_sqrtf(d);
        float fac = (t.y < 0.0f) ? 1.0f : sq;       // kr==1 ? d : d^1.5
        float arg = fmaf(-fabsf(t.y), d * fac, e);
        float ex  = __builtin_amdgcn_exp2f(arg);    // 0 outside cutoff
        float rep = t.x * __builtin_amdgcn_rcpf(d) * ex;
        unsigned mol = (unsigned)(((unsigned long long)ua0 * molMagic) >> 42);
        atomicAdd(&acc[mol], rep);
    };

    auto process = [&](int4 i0, int4 i1, float4 dv) {
        pair((unsigned)i0.x, (unsigned)i1.x, dv.x);
        pair((unsigned)i0.y, (unsigned)i1.y, dv.y);
        pair((unsigned)i0.z, (unsigned)i1.z, dv.z);
        pair((unsigned)i0.w, (unsigned)i1.w, dv.w);
    };

    long long P4 = P >> 2;
    long long gstride = (long long)gridDim.x * nthr;
    long long i = (long long)blockIdx.x * nthr + tid;

    // -------- main loop: 1-deep register prefetch across the backedge ------
    if (i < P4) {
        int4   c0 = nb04[i];
        int4   c1 = nb14[i];
        float4 cd = dv4[i];
        long long j = i + gstride;
        while (true) {
            bool more = (j < P4);
            long long js = more ? j : i;     // safe addr on last trip
            int4   n0 = nb04[js];            // prefetch next group
            int4   n1 = nb14[js];
            float4 nd = dv4[js];
            __builtin_amdgcn_sched_barrier(0);  // loads stay above consume
            process(c0, c1, cd);             // waits vmcnt(3): prefetch stays in flight
            if (!more) break;
            c0 = n0; c1 = n1; cd = nd;
            j += gstride;
        }
    }

    // tail (P not divisible by 4) — handled by block 0 (empty for P=8.4M)
    long long tail0 = P4 << 2;
    if (blockIdx.x == 0) {
        const int* nb0 = nbr;
        const int* nb1 = nbr + P;
        for (long long p = tail0 + tid; p < P; p += nthr)
            pair((unsigned)nb0[p], (unsigned)nb1[p], dist[p]);
    }
    __syncthreads();

    if (mode == 0) {
        float* row = partials + (size_t)blockIdx.x * (size_t)M;
        for (int m = tid; m < M; m += nthr) row[m] = acc[m];
    } else {
        for (int m = tid; m < M; m += nthr) {
            float v = acc[m];
            if (v != 0.0f) atomicAdd(&out[m], v);
        }
    }
}

// ---------------- kernel 3: column-sum the partial rows ---------------------
__global__ __launch_bounds__(256) void reduce_kernel(
    const float* __restrict__ partials, float* __restrict__ out,
    int M, int nblk, int rows_per)
{
    int m = blockIdx.x * blockDim.x + threadIdx.x;
    if (m >= M) return;
    int r0 = blockIdx.y * rows_per;
    int r1 = r0 + rows_per;
    if (r1 > nblk) r1 = nblk;
    if (r0 >= r1) return;
    float s0 = 0.f, s1 = 0.f, s2 = 0.f, s3 = 0.f;
    int r = r0;
    for (; r + 3 < r1; r += 4) {
        s0 += partials[(size_t)(r + 0) * M + m];
        s1 += partials[(size_t)(r + 1) * M + m];
        s2 += partials[(size_t)(r + 2) * M + m];
        s3 += partials[(size_t)(r + 3) * M + m];
    }
    for (; r < r1; ++r) s0 += partials[(size_t)r * M + m];
    atomicAdd(&out[m], (s0 + s1) + (s2 + s3));
}

extern "C" void kernel_launch(void* const* d_in, const int* in_sizes, int n_in,
                              void* d_out, int out_size, void* d_ws, size_t ws_size,
                              hipStream_t stream)
{
    const int*   elem  = (const int*)d_in[0];
    const int*   nbr   = (const int*)d_in[1];
    const float* dist  = (const float*)d_in[2];
    const float* y_ab  = (const float*)d_in[3];
    const float* sa_ab = (const float*)d_in[4];
    const float* kr_ab = (const float*)d_in[5];
    float* out = (float*)d_out;

    const int natoms = in_sizes[0];
    const long long P = (long long)in_sizes[2];
    const int M = out_size;
    const int A = natoms / M;
    // exact floor(a0/A) for a0 < 2^21 via magic multiply: magic = ceil(2^42/A)
    unsigned long long molMagic =
        (A > 0) ? ((((unsigned long long)1 << 42) + (unsigned long long)A - 1)
                   / (unsigned long long)A)
                : 1ull;
    const int nwords = (natoms + 15) / 16;

    // workspace layout: [packed: nwords u32 (256B aligned)][partials: nblk*M f32]
    size_t packed_bytes = ((size_t)nwords * 4 + 255) & ~(size_t)255;
    bool have_packed = (ws_size >= packed_bytes);
    unsigned* packed = have_packed ? (unsigned*)d_ws : nullptr;
    if (!have_packed) return;  // harness always provides workspace

    const int BLOCK = 1024;
    int nblk = 512;            // 2 blocks/CU on 256 CUs -> 32 waves/CU
    float* partials = nullptr;
    int mode = 1;              // global-atomic fallback
    {
        size_t avail = ws_size - packed_bytes;
        size_t rowb = (size_t)M * 4;
        long long maxrows = (long long)(avail / rowb);
        if (maxrows >= 64) {
            nblk = (int)(maxrows < 512 ? maxrows : 512);
            partials = (float*)((char*)d_ws + packed_bytes);
            mode = 0;
        }
    }

    // kernel 1: pack + zero out
    {
        int total = (nwords > M) ? nwords : M;
        int g = (total + 255) / 256;
        hipLaunchKernelGGL(pack_zero_kernel, dim3(g), dim3(256), 0, stream,
                           elem, natoms, nwords, packed, out, M);
    }

    // kernel 2: main
    {
        size_t smem = (size_t)M * 4 + 16 * sizeof(float2) + (size_t)nwords * 4;
        hipLaunchKernelGGL(rep_main_kernel, dim3(nblk), dim3(BLOCK), smem, stream,
                           nbr, dist, packed, y_ab, sa_ab, kr_ab,
                           P, M, nwords, molMagic, A, partials, out, mode);
    }

    // kernel 3: reduce partial rows
    if (mode == 0) {
        const int SPLIT = 32;
        int rows_per = (nblk + SPLIT - 1) / SPLIT;
        dim3 grid((M + 255) / 256, SPLIT);
        hipLaunchKernelGGL(reduce_kernel, grid, dim3(256), 0, stream,
                           partials, out, M, nblk, rows_per);
    }
}

// Round 4
// 156.008 us; speedup vs baseline: 1.0211x; 1.0211x over previous
//
#include <hip/hip_runtime.h>

// RepulsionXTB: per-pair repulsion energy, segment-summed per molecule.
//
// Inputs (setup_inputs order, harness converts ints to int32):
//   d_in[0] element_idxs  int32  [M*A]   (M=2048, A=64 -> 131072)
//   d_in[1] neighbor_idxs int32  [2*P]   (P=8388608)
//   d_in[2] distances     f32    [P]
//   d_in[3] y_ab          f32    [16]
//   d_in[4] sqrt_alpha_ab f32    [16]
//   d_in[5] k_rep_ab      f32    [16]   (1.5 everywhere except [0,0]=1.0)
// Output: energies f32 [M]
//
// R7 notes: R4-R6 established the kernel is MLP-bound, not latency/VALU/
// LDS/BW-bound: each wave kept only 3x16B loads in flight -> device
// in-flight ~0.4MB vs ~1.8MB needed to saturate ~6TB/s at ~290ns latency
// -> effective BW capped at the measured ~2.2TB/s. Fix: unroll the
// grid-stride loop 4x with all 12 independent 16B loads hoisted and
// fenced (sched_barrier) before processing 16 pairs -> 192B/lane in
// flight during the single stall (4x MLP). For P4 = 4*gridstride the
// fast path runs exactly once per lane.

#define AB_D 1.8897261258369282
#define L2E  1.4426950408889634f   // log2(e)

// ---------------- kernel 1: pack species to 2 bits/atom + zero output -------
__global__ __launch_bounds__(256) void pack_zero_kernel(
    const int* __restrict__ elem, int natoms, int nwords,
    unsigned* __restrict__ packed, float* __restrict__ out, int M)
{
    int g = blockIdx.x * blockDim.x + threadIdx.x;
    if (g < M) out[g] = 0.0f;
    if (packed != nullptr && g < nwords) {
        int base = g * 16;
        unsigned w = 0u;
        if (base + 16 <= natoms) {
            const int4* p = (const int4*)(elem + base);
            #pragma unroll
            for (int q = 0; q < 4; ++q) {
                int4 v = p[q];
                w |= ((unsigned)v.x & 3u) << (2 * (4 * q + 0));
                w |= ((unsigned)v.y & 3u) << (2 * (4 * q + 1));
                w |= ((unsigned)v.z & 3u) << (2 * (4 * q + 2));
                w |= ((unsigned)v.w & 3u) << (2 * (4 * q + 3));
            }
        } else {
            for (int j = 0; j < 16; ++j) {
                int a = base + j;
                unsigned s = (a < natoms) ? ((unsigned)elem[a] & 3u) : 0u;
                w |= s << (2 * j);
            }
        }
        packed[g] = w;
    }
}

// ---------------- kernel 2: main pair loop ----------------------------------
// LDS layout: [acc: M f32][tbl: 16 float2][pk: nwords u32]
__global__ __launch_bounds__(1024, 8) void rep_main_kernel(
    const int* __restrict__ nbr, const float* __restrict__ dist,
    const unsigned* __restrict__ packed_g,
    const float* __restrict__ y_ab, const float* __restrict__ sa_ab,
    const float* __restrict__ kr_ab,
    long long P, int M, int nwords, unsigned long long molMagic, int A,
    float* __restrict__ partials, float* __restrict__ out,
    int mode /*0 = write partial row, 1 = global atomics*/)
{
    extern __shared__ char smem[];
    float*  acc = (float*)smem;
    float2* tbl = (float2*)(smem + (size_t)M * 4);
    unsigned* pk = (unsigned*)(smem + (size_t)M * 4 + 16 * sizeof(float2));

    const int tid = threadIdx.x;
    const int nthr = blockDim.x;

    for (int m = tid; m < M; m += nthr) acc[m] = 0.0f;
    {   // vectorized pk staging (nwords is a multiple of 4 for A*M mult of 64)
        int nw4 = nwords >> 2;
        const uint4* src4 = (const uint4*)packed_g;
        uint4* dst4 = (uint4*)pk;
        for (int w = tid; w < nw4; w += nthr) dst4[w] = src4[w];
        for (int w = (nw4 << 2) + tid; w < nwords; w += nthr) pk[w] = packed_g[w];
    }
    if (tid < 16) {
        float sa = sa_ab[tid] * L2E;           // pre-scale for exp2
        if (kr_ab[tid] == 1.0f) sa = -sa;      // sign bit encodes kr==1 (H-H)
        tbl[tid] = make_float2(y_ab[tid], sa);
    }
    __syncthreads();

    const float ABf   = (float)AB_D;
    const float DMIN  = (float)(1e-7 * AB_D);
    const float RCINV = (float)(1.0 / (5.2 * AB_D));

    const int4*   nb04 = (const int4*)nbr;
    const int4*   nb14 = (const int4*)(nbr + P);
    const float4* dv4  = (const float4*)dist;

    // per-pair chain: 2 pk reads -> tbl read -> VALU -> LDS atomic
    auto pair = [&](unsigned ua0, unsigned ua1, float draw) {
        unsigned w0 = pk[ua0 >> 4];
        unsigned w1 = pk[ua1 >> 4];
        unsigned s0 = (w0 >> ((ua0 & 15u) * 2u)) & 3u;
        unsigned s1 = (w1 >> ((ua1 & 15u) * 2u)) & 3u;
        float2 t = tbl[s0 * 4u + s1];
        float d   = fmaxf(draw * ABf, DMIN);
        float x   = d * RCINV;
        float om  = fmaxf(fmaf(-x, x, 1.0f), 0.0f); // 0 outside cutoff
        float r   = __builtin_amdgcn_rcpf(om);      // +inf outside
        float e   = fmaf(-L2E, r, L2E);             // -inf outside
        float sq  = __builtin_amdgcn_sqrtf(d);
        float fac = (t.y < 0.0f) ? 1.0f : sq;       // kr==1 ? d : d^1.5
        float arg = fmaf(-fabsf(t.y), d * fac, e);
        float ex  = __builtin_amdgcn_exp2f(arg);    // 0 outside cutoff
        float rep = t.x * __builtin_amdgcn_rcpf(d) * ex;
        unsigned mol = (unsigned)(((unsigned long long)ua0 * molMagic) >> 42);
        atomicAdd(&acc[mol], rep);
    };

    auto process = [&](int4 i0, int4 i1, float4 dv) {
        pair((unsigned)i0.x, (unsigned)i1.x, dv.x);
        pair((unsigned)i0.y, (unsigned)i1.y, dv.y);
        pair((unsigned)i0.z, (unsigned)i1.z, dv.z);
        pair((unsigned)i0.w, (unsigned)i1.w, dv.w);
    };

    long long P4 = P >> 2;
    long long gstride = (long long)gridDim.x * nthr;
    long long mega = gstride << 2;

    // -------- main loop: 4x unroll, 12 hoisted loads = 192B/lane in flight --
    for (long long i = (long long)blockIdx.x * nthr + tid; i < P4; i += mega) {
        long long j1 = i + gstride, j2 = i + 2 * gstride, j3 = i + 3 * gstride;
        if (j3 < P4) {
            int4   A0 = nb04[i];  int4   A1 = nb04[j1];
            int4   A2 = nb04[j2]; int4   A3 = nb04[j3];
            int4   B0 = nb14[i];  int4   B1 = nb14[j1];
            int4   B2 = nb14[j2]; int4   B3 = nb14[j3];
            float4 D0 = dv4[i];   float4 D1 = dv4[j1];
            float4 D2 = dv4[j2];  float4 D3 = dv4[j3];
            __builtin_amdgcn_sched_barrier(0);  // loads stay issued above
            process(A0, B0, D0);
            process(A1, B1, D1);
            process(A2, B2, D2);
            process(A3, B3, D3);
        } else {
            for (long long j = i; j < P4; j += gstride)
                process(nb04[j], nb14[j], dv4[j]);
        }
    }

    // tail (P not divisible by 4) — handled by block 0 (empty for P=8.4M)
    long long tail0 = P4 << 2;
    if (blockIdx.x == 0) {
        const int* nb0 = nbr;
        const int* nb1 = nbr + P;
        for (long long p = tail0 + tid; p < P; p += nthr)
            pair((unsigned)nb0[p], (unsigned)nb1[p], dist[p]);
    }
    __syncthreads();

    if (mode == 0) {
        float* row = partials + (size_t)blockIdx.x * (size_t)M;
        for (int m = tid; m < M; m += nthr) row[m] = acc[m];
    } else {
        for (int m = tid; m < M; m += nthr) {
            float v = acc[m];
            if (v != 0.0f) atomicAdd(&out[m], v);
        }
    }
}

// ---------------- kernel 3: column-sum the partial rows ---------------------
__global__ __launch_bounds__(256) void reduce_kernel(
    const float* __restrict__ partials, float* __restrict__ out,
    int M, int nblk, int rows_per)
{
    int m = blockIdx.x * blockDim.x + threadIdx.x;
    if (m >= M) return;
    int r0 = blockIdx.y * rows_per;
    int r1 = r0 + rows_per;
    if (r1 > nblk) r1 = nblk;
    if (r0 >= r1) return;
    float s0 = 0.f, s1 = 0.f, s2 = 0.f, s3 = 0.f;
    int r = r0;
    for (; r + 3 < r1; r += 4) {
        s0 += partials[(size_t)(r + 0) * M + m];
        s1 += partials[(size_t)(r + 1) * M + m];
        s2 += partials[(size_t)(r + 2) * M + m];
        s3 += partials[(size_t)(r + 3) * M + m];
    }
    for (; r < r1; ++r) s0 += partials[(size_t)r * M + m];
    atomicAdd(&out[m], (s0 + s1) + (s2 + s3));
}

extern "C" void kernel_launch(void* const* d_in, const int* in_sizes, int n_in,
                              void* d_out, int out_size, void* d_ws, size_t ws_size,
                              hipStream_t stream)
{
    const int*   elem  = (const int*)d_in[0];
    const int*   nbr   = (const int*)d_in[1];
    const float* dist  = (const float*)d_in[2];
    const float* y_ab  = (const float*)d_in[3];
    const float* sa_ab = (const float*)d_in[4];
    const float* kr_ab = (const float*)d_in[5];
    float* out = (float*)d_out;

    const int natoms = in_sizes[0];
    const long long P = (long long)in_sizes[2];
    const int M = out_size;
    const int A = natoms / M;
    // exact floor(a0/A) for a0 < 2^21 via magic multiply: magic = ceil(2^42/A)
    unsigned long long molMagic =
        (A > 0) ? ((((unsigned long long)1 << 42) + (unsigned long long)A - 1)
                   / (unsigned long long)A)
                : 1ull;
    const int nwords = (natoms + 15) / 16;

    // workspace layout: [packed: nwords u32 (256B aligned)][partials: nblk*M f32]
    size_t packed_bytes = ((size_t)nwords * 4 + 255) & ~(size_t)255;
    bool have_packed = (ws_size >= packed_bytes);
    unsigned* packed = have_packed ? (unsigned*)d_ws : nullptr;
    if (!have_packed) return;  // harness always provides workspace

    const int BLOCK = 1024;
    int nblk = 512;            // 2 blocks/CU on 256 CUs -> 32 waves/CU
    float* partials = nullptr;
    int mode = 1;              // global-atomic fallback
    {
        size_t avail = ws_size - packed_bytes;
        size_t rowb = (size_t)M * 4;
        long long maxrows = (long long)(avail / rowb);
        if (maxrows >= 64) {
            nblk = (int)(maxrows < 512 ? maxrows : 512);
            partials = (float*)((char*)d_ws + packed_bytes);
            mode = 0;
        }
    }

    // kernel 1: pack + zero out
    {
        int total = (nwords > M) ? nwords : M;
        int g = (total + 255) / 256;
        hipLaunchKernelGGL(pack_zero_kernel, dim3(g), dim3(256), 0, stream,
                           elem, natoms, nwords, packed, out, M);
    }

    // kernel 2: main
    {
        size_t smem = (size_t)M * 4 + 16 * sizeof(float2) + (size_t)nwords * 4;
        hipLaunchKernelGGL(rep_main_kernel, dim3(nblk), dim3(BLOCK), smem, stream,
                           nbr, dist, packed, y_ab, sa_ab, kr_ab,
                           P, M, nwords, molMagic, A, partials, out, mode);
    }

    // kernel 3: reduce partial rows
    if (mode == 0) {
        const int SPLIT = 32;
        int rows_per = (nblk + SPLIT - 1) / SPLIT;
        dim3 grid((M + 255) / 256, SPLIT);
        hipLaunchKernelGGL(reduce_kernel, grid, dim3(256), 0, stream,
                           partials, out, M, nblk, rows_per);
    }
}